// Round 4
// baseline (6063.481 us; speedup 1.0000x reference)
//
#include <hip/hip_runtime.h>

#define NN 100000
#define NE 3200000
#define NA 60000
#define NB 40000
#define NHID 256
#define NOUT 64

#define RPB 64                    // rows per bucket
#define NBUCK 1563                // ceil(NN/64)
#define PBLK 256                  // partition blocks
#define CHUNK 12500               // NE / PBLK (exact)

typedef unsigned short u16;
typedef unsigned int u32;
typedef __attribute__((ext_vector_type(8))) short short8;
typedef __attribute__((ext_vector_type(4))) float f32x4;

__device__ __forceinline__ float bf2f(u16 u) {
  return __uint_as_float(((u32)u) << 16);
}
__device__ __forceinline__ u16 f2bf(float f) {
  u32 u = __float_as_uint(f);
  u32 r = (u + 0x7fffu + ((u >> 16) & 1u)) >> 16;  // RNE
  return (u16)r;
}

__device__ __forceinline__ void gload_lds16(const void* gsrc, void* ldst) {
  __builtin_amdgcn_global_load_lds(
      (const __attribute__((address_space(1))) void*)gsrc,
      (__attribute__((address_space(3))) void*)ldst, 16, 0, 0);
}

// ---------------------------------------------------------------------------
// bf16 MFMA GEMM (unchanged from round 3): C = A @ Bt^T + bias, opt relu.
// ---------------------------------------------------------------------------
template <int BN, int RELU_OUT>
__global__ __launch_bounds__(256) void gemm_mfma(
    const u16* __restrict__ A, const u16* __restrict__ Bt,
    const float* __restrict__ bias, u16* __restrict__ C,
    int M, int N, int K) {
  constexpr int BM = 128;
  constexpr int FI = (BN == 128) ? 4 : 2;
  constexpr int WROWS = FI * 16;
  __shared__ __align__(16) u16 As[BM * 32];
  __shared__ __align__(16) u16 Bs[BN * 32];

  const int tid = threadIdx.x;
  const int w = tid >> 6;
  const int lane = tid & 63;
  const int bm = blockIdx.x * BM;
  const int bn = blockIdx.y * BN;
  const int wr = (BN == 128) ? (w >> 1) : w;
  const int wc = (BN == 128) ? (w & 1) : 0;

  f32x4 acc[FI][4];
#pragma unroll
  for (int i = 0; i < FI; ++i)
#pragma unroll
    for (int j = 0; j < 4; ++j) acc[i][j] = (f32x4)0.f;

  for (int k0 = 0; k0 < K; k0 += 32) {
#pragma unroll
    for (int s = 0; s < 2; ++s) {
      const int inst = w * 2 + s;
      const int row = inst * 16 + (lane >> 2);
      int rg = bm + row;
      if (rg > M - 1) rg = M - 1;
      const int c = (lane & 3) ^ ((row >> 1) & 3);
      gload_lds16(A + (size_t)rg * K + k0 + c * 8, &As[inst * 512]);
    }
    if (BN == 128) {
#pragma unroll
      for (int s = 0; s < 2; ++s) {
        const int inst = w * 2 + s;
        const int row = inst * 16 + (lane >> 2);
        const int c = (lane & 3) ^ ((row >> 1) & 3);
        gload_lds16(Bt + (size_t)(bn + row) * K + k0 + c * 8,
                    &Bs[inst * 512]);
      }
    } else {
      const int inst = w;
      const int row = inst * 16 + (lane >> 2);
      const int c = (lane & 3) ^ ((row >> 1) & 3);
      gload_lds16(Bt + (size_t)(bn + row) * K + k0 + c * 8, &Bs[inst * 512]);
    }
    __syncthreads();

    const int kc = lane >> 4;
    short8 af[FI], bfr[4];
#pragma unroll
    for (int i = 0; i < FI; ++i) {
      const int row = wr * WROWS + i * 16 + (lane & 15);
      const int ch = kc ^ ((row >> 1) & 3);
      af[i] = *reinterpret_cast<const short8*>(&As[row * 32 + ch * 8]);
    }
#pragma unroll
    for (int j = 0; j < 4; ++j) {
      const int row = wc * 64 + j * 16 + (lane & 15);
      const int ch = kc ^ ((row >> 1) & 3);
      bfr[j] = *reinterpret_cast<const short8*>(&Bs[row * 32 + ch * 8]);
    }
#pragma unroll
    for (int i = 0; i < FI; ++i)
#pragma unroll
      for (int j = 0; j < 4; ++j)
        acc[i][j] = __builtin_amdgcn_mfma_f32_16x16x32_bf16(af[i], bfr[j],
                                                            acc[i][j], 0, 0, 0);
    __syncthreads();
  }

#pragma unroll
  for (int i = 0; i < FI; ++i) {
#pragma unroll
    for (int j = 0; j < 4; ++j) {
      const int col = bn + wc * 64 + j * 16 + (lane & 15);
      const float bv = bias[col];
#pragma unroll
      for (int r = 0; r < 4; ++r) {
        const int row = bm + wr * WROWS + i * 16 + (lane >> 4) * 4 + r;
        if (row < M) {
          float o = acc[i][j][r] + bv;
          if (RELU_OUT) o = fmaxf(o, 0.f);
          C[(size_t)row * N + col] = f2bf(o);
        }
      }
    }
  }
}

// ---------------------------------------------------------------------------
// conversions
// ---------------------------------------------------------------------------
__global__ __launch_bounds__(256) void cvt_bf16(const float4* __restrict__ in,
                                                ushort4* __restrict__ out,
                                                int n4) {
  const int i = blockIdx.x * 256 + threadIdx.x;
  if (i >= n4) return;
  const float4 v = in[i];
  ushort4 o;
  o.x = f2bf(v.x); o.y = f2bf(v.y); o.z = f2bf(v.z); o.w = f2bf(v.w);
  out[i] = o;
}

__global__ __launch_bounds__(256) void wt_transpose(const float* __restrict__ W,
                                                    u16* __restrict__ Wt,
                                                    int K, int N) {
  const int i = blockIdx.x * 256 + threadIdx.x;
  if (i >= N * K) return;
  const int n = i / K;
  const int k = i - n * K;
  Wt[i] = f2bf(W[(size_t)k * N + n]);
}

// ---------------------------------------------------------------------------
// Bucket radix partition: rows -> 1563 buckets of 64 rows.
// P1: per-block LDS histogram -> cnt[bucket][block]
// S1: per-bucket exclusive scan over 256 block counts (in-place) + totals
// S2: exclusive scan of bucket totals -> bstart
// P3: scatter edges to bucket regions via LDS cursors (no global atomics)
// ---------------------------------------------------------------------------
__global__ __launch_bounds__(256) void p1_hist(const int* __restrict__ rows,
                                               int* __restrict__ cnt) {
  __shared__ int h[NBUCK];
  const int tid = threadIdx.x;
  for (int i = tid; i < NBUCK; i += 256) h[i] = 0;
  __syncthreads();
  const int s = blockIdx.x * CHUNK;
  const int e = s + CHUNK;
  for (int i = s + tid; i < e && i < NE; i += 256)
    atomicAdd(&h[rows[i] >> 6], 1);
  __syncthreads();
  for (int i = tid; i < NBUCK; i += 256) cnt[i * PBLK + blockIdx.x] = h[i];
}

__global__ __launch_bounds__(256) void s1_scan_blocks(int* __restrict__ cnt,
                                                      int* __restrict__ btot) {
  __shared__ int lds[256];
  const int bu = blockIdx.x;
  const int t = threadIdx.x;
  const int v = cnt[bu * PBLK + t];
  lds[t] = v;
  __syncthreads();
#pragma unroll
  for (int off = 1; off < 256; off <<= 1) {
    const int x = (t >= off) ? lds[t - off] : 0;
    __syncthreads();
    lds[t] += x;
    __syncthreads();
  }
  cnt[bu * PBLK + t] = lds[t] - v;  // exclusive within bucket
  if (t == 255) btot[bu] = lds[255];
}

__global__ __launch_bounds__(1024) void s2_scan_buckets(
    const int* __restrict__ btot, int* __restrict__ bstart) {
  __shared__ int lds[1024];
  __shared__ int carry;
  const int t = threadIdx.x;
  if (t == 0) carry = 0;
  __syncthreads();
  for (int base = 0; base < NBUCK; base += 1024) {
    const int i = base + t;
    const int v = (i < NBUCK) ? btot[i] : 0;
    lds[t] = v;
    __syncthreads();
#pragma unroll
    for (int off = 1; off < 1024; off <<= 1) {
      const int x = (t >= off) ? lds[t - off] : 0;
      __syncthreads();
      lds[t] += x;
      __syncthreads();
    }
    const int excl = lds[t] - v;
    const int c = carry;
    if (i < NBUCK) bstart[i] = c + excl;
    __syncthreads();
    if (t == 0) carry = c + lds[1023];
    __syncthreads();
  }
  if (t == 0) bstart[NBUCK] = NE;
}

__global__ __launch_bounds__(256) void p3_scatter(
    const int* __restrict__ rows, const int* __restrict__ cols,
    const float* __restrict__ vals, const int* __restrict__ cnt,
    const int* __restrict__ bstart, int2* __restrict__ edges) {
  __shared__ int lcur[NBUCK];
  const int tid = threadIdx.x;
  const int blk = blockIdx.x;
  for (int bu = tid; bu < NBUCK; bu += 256)
    lcur[bu] = bstart[bu] + cnt[bu * PBLK + blk];
  __syncthreads();
  const int s = blk * CHUNK;
  const int e = s + CHUNK;
  for (int i = s + tid; i < e && i < NE; i += 256) {
    const int r = rows[i];
    const int bu = r >> 6;
    const int lr = r & 63;
    const int pos = atomicAdd(&lcur[bu], 1);
    edges[pos] = make_int2(cols[i] | (lr << 17), __float_as_int(vals[i]));
  }
}

// ---------------------------------------------------------------------------
// Bucket SpMM width 256: one block per bucket, fp32 acc tile in LDS (64KB).
// 1024 threads (16 waves); each wave owns one edge/iter; lane covers feature
// lane, 64+lane, 128+lane, 192+lane -> ds_add 2 lanes/bank (free).
// Epilogue: relu + bf16, streaming.
// ---------------------------------------------------------------------------
__global__ __launch_bounds__(1024) void spmm256_lds(
    const int* __restrict__ bstart, const int2* __restrict__ edges,
    const u16* __restrict__ Zb, u16* __restrict__ Yb) {
  __shared__ float sacc[RPB * 256];  // 64KB
  const int tid = threadIdx.x;
  const int bu = blockIdx.x;
  for (int i = tid; i < RPB * 256 / 4; i += 1024)
    reinterpret_cast<float4*>(sacc)[i] = make_float4(0.f, 0.f, 0.f, 0.f);
  __syncthreads();

  const int w = tid >> 6;
  const int lane = tid & 63;
  const int ee = bstart[bu + 1];
#pragma unroll 2
  for (int e = bstart[bu] + w; e < ee; e += 16) {
    const int2 ed = edges[e];
    const int col = ed.x & 0x1FFFF;
    const int lr = (ed.x >> 17) & 63;
    const float v = __int_as_float(ed.y);
    const u16* zr = Zb + (size_t)col * 256;
    const float x0 = bf2f(zr[lane]);
    const float x1 = bf2f(zr[64 + lane]);
    const float x2 = bf2f(zr[128 + lane]);
    const float x3 = bf2f(zr[192 + lane]);
    float* ar = sacc + lr * 256 + lane;
    atomicAdd(ar, v * x0);
    atomicAdd(ar + 64, v * x1);
    atomicAdd(ar + 128, v * x2);
    atomicAdd(ar + 192, v * x3);
  }
  __syncthreads();

  for (int i = tid; i < RPB * 256 / 4; i += 1024) {
    const int row = i >> 6;
    const int grow = bu * RPB + row;
    if (grow >= NN) continue;
    const int c = (i & 63) * 4;
    const float4 a = *reinterpret_cast<const float4*>(&sacc[row * 256 + c]);
    ushort4 o;
    o.x = f2bf(fmaxf(a.x, 0.f));
    o.y = f2bf(fmaxf(a.y, 0.f));
    o.z = f2bf(fmaxf(a.z, 0.f));
    o.w = f2bf(fmaxf(a.w, 0.f));
    *reinterpret_cast<ushort4*>(&Yb[(size_t)grow * 256 + c]) = o;
  }
}

// ---------------------------------------------------------------------------
// Bucket SpMM width 64: fp32 acc tile 16KB, 512 threads (8 waves).
// ---------------------------------------------------------------------------
__global__ __launch_bounds__(512) void spmm64_lds(
    const int* __restrict__ bstart, const int2* __restrict__ edges,
    const u16* __restrict__ Zb, float* __restrict__ Y) {
  __shared__ float sacc[RPB * 64];  // 16KB
  const int tid = threadIdx.x;
  const int bu = blockIdx.x;
  for (int i = tid; i < RPB * 64 / 4; i += 512)
    reinterpret_cast<float4*>(sacc)[i] = make_float4(0.f, 0.f, 0.f, 0.f);
  __syncthreads();

  const int w = tid >> 6;
  const int lane = tid & 63;
  const int ee = bstart[bu + 1];
#pragma unroll 2
  for (int e = bstart[bu] + w; e < ee; e += 8) {
    const int2 ed = edges[e];
    const int col = ed.x & 0x1FFFF;
    const int lr = (ed.x >> 17) & 63;
    const float v = __int_as_float(ed.y);
    const float x = bf2f(Zb[(size_t)col * 64 + lane]);
    atomicAdd(&sacc[lr * 64 + lane], v * x);
  }
  __syncthreads();

  for (int i = tid; i < RPB * 64 / 4; i += 512) {
    const int row = i >> 4;
    const int grow = bu * RPB + row;
    if (grow >= NN) continue;
    const int c = (i & 15) * 4;
    const float4 a = *reinterpret_cast<const float4*>(&sacc[row * 64 + c]);
    *reinterpret_cast<float4*>(&Y[(size_t)grow * 64 + c]) = a;
  }
}

extern "C" void kernel_launch(void* const* d_in, const int* in_sizes, int n_in,
                              void* d_out, int out_size, void* d_ws,
                              size_t ws_size, hipStream_t stream) {
  const float* x_a  = (const float*)d_in[0];
  const float* x_b  = (const float*)d_in[1];
  const int*   rows = (const int*)d_in[2];
  const int*   cols = (const int*)d_in[3];
  const float* vals = (const float*)d_in[4];
  const float* W1a  = (const float*)d_in[5];
  const float* b1a  = (const float*)d_in[6];
  const float* W1b  = (const float*)d_in[7];
  const float* b1b  = (const float*)d_in[8];
  const float* Wf   = (const float*)d_in[9];
  const float* bf   = (const float*)d_in[10];
  const float* W2   = (const float*)d_in[11];
  const float* b2   = (const float*)d_in[12];
  float* out = (float*)d_out;

  // workspace (~184 MB)
  char* p = (char*)d_ws;
  u16* h    = (u16*)p;  p += (size_t)NN * NHID * 2;   // h, later s1b
  u16* zb   = (u16*)p;  p += (size_t)NN * NHID * 2;
  u16* z2b  = (u16*)p;  p += (size_t)NN * NOUT * 2;
  u16* xab  = (u16*)p;  p += (size_t)NA * 256 * 2;
  u16* xbb  = (u16*)p;  p += (size_t)NB * 128 * 2;
  u16* W1at = (u16*)p;  p += 256 * 256 * 2;
  u16* W1bt = (u16*)p;  p += 256 * 128 * 2;
  u16* Wft  = (u16*)p;  p += 256 * 256 * 2;
  u16* W2t  = (u16*)p;  p += 64 * 256 * 2;
  int2* edges = (int2*)p; p += (size_t)NE * 8;
  int* cnt    = (int*)p;  p += (size_t)NBUCK * PBLK * 4;  // 1.6MB
  int* btot   = (int*)p;  p += (size_t)((NBUCK + 3) & ~3) * 4;
  int* bstart = (int*)p;  p += (size_t)((NBUCK + 4) & ~3) * 4;
  u16* s1b = h;

  // --- bucket partition (no global atomics) ---
  p1_hist<<<PBLK, 256, 0, stream>>>(rows, cnt);
  s1_scan_blocks<<<NBUCK, 256, 0, stream>>>(cnt, btot);
  s2_scan_buckets<<<1, 1024, 0, stream>>>(btot, bstart);
  p3_scatter<<<PBLK, 256, 0, stream>>>(rows, cols, vals, cnt, bstart, edges);

  // --- input / weight conversion ---
  cvt_bf16<<<(NA * 256 / 4 + 255) / 256, 256, 0, stream>>>(
      (const float4*)x_a, (ushort4*)xab, NA * 256 / 4);
  cvt_bf16<<<(NB * 128 / 4 + 255) / 256, 256, 0, stream>>>(
      (const float4*)x_b, (ushort4*)xbb, NB * 128 / 4);
  wt_transpose<<<(256 * 256 + 255) / 256, 256, 0, stream>>>(W1a, W1at, 256, 256);
  wt_transpose<<<(256 * 128 + 255) / 256, 256, 0, stream>>>(W1b, W1bt, 128, 256);
  wt_transpose<<<(256 * 256 + 255) / 256, 256, 0, stream>>>(Wf, Wft, 256, 256);
  wt_transpose<<<(64 * 256 + 255) / 256, 256, 0, stream>>>(W2, W2t, 256, 64);

  // --- dense pipeline ---
  gemm_mfma<128, 1><<<dim3((NA + 127) / 128, 2), 256, 0, stream>>>(
      xab, W1at, b1a, h, NA, NHID, 256);
  gemm_mfma<128, 1><<<dim3((NB + 127) / 128, 2), 256, 0, stream>>>(
      xbb, W1bt, b1b, h + (size_t)NA * NHID, NB, NHID, 128);
  gemm_mfma<128, 0><<<dim3((NN + 127) / 128, 2), 256, 0, stream>>>(
      h, Wft, bf, zb, NN, NHID, 256);
  // s1b = bf16(relu(spmm(zb)))
  spmm256_lds<<<NBUCK, 1024, 0, stream>>>(bstart, edges, zb, s1b);
  gemm_mfma<64, 0><<<dim3((NN + 127) / 128, 1), 256, 0, stream>>>(
      s1b, W2t, b2, z2b, NN, NOUT, 256);
  // out = spmm(z2b)
  spmm64_lds<<<NBUCK, 512, 0, stream>>>(bstart, edges, z2b, out);
}

// Round 5
// 589.099 us; speedup vs baseline: 10.2928x; 10.2928x over previous
//
#include <hip/hip_runtime.h>

#define NN 100000
#define NE 3200000
#define NA 60000
#define NB 40000
#define NHID 256
#define NOUT 64

#define RPB 64                    // rows per bucket
#define NBUCK 1563                // ceil(NN/64)
#define PBLK 256                  // partition blocks
#define CHUNK 12500               // NE / PBLK (exact)

typedef unsigned short u16;
typedef unsigned int u32;
typedef __attribute__((ext_vector_type(8))) short short8;
typedef __attribute__((ext_vector_type(4))) float f32x4;

__device__ __forceinline__ float bf2f(u16 u) {
  return __uint_as_float(((u32)u) << 16);
}
__device__ __forceinline__ u16 f2bf(float f) {
  u32 u = __float_as_uint(f);
  u32 r = (u + 0x7fffu + ((u >> 16) & 1u)) >> 16;  // RNE
  return (u16)r;
}

__device__ __forceinline__ void gload_lds16(const void* gsrc, void* ldst) {
  __builtin_amdgcn_global_load_lds(
      (const __attribute__((address_space(1))) void*)gsrc,
      (__attribute__((address_space(3))) void*)ldst, 16, 0, 0);
}

// ---------------------------------------------------------------------------
// bf16 MFMA GEMM (round-3 proven): C = A @ Bt^T + bias, opt relu.
// ---------------------------------------------------------------------------
template <int BN, int RELU_OUT>
__global__ __launch_bounds__(256) void gemm_mfma(
    const u16* __restrict__ A, const u16* __restrict__ Bt,
    const float* __restrict__ bias, u16* __restrict__ C,
    int M, int N, int K) {
  constexpr int BM = 128;
  constexpr int FI = (BN == 128) ? 4 : 2;
  constexpr int WROWS = FI * 16;
  __shared__ __align__(16) u16 As[BM * 32];
  __shared__ __align__(16) u16 Bs[BN * 32];

  const int tid = threadIdx.x;
  const int w = tid >> 6;
  const int lane = tid & 63;
  const int bm = blockIdx.x * BM;
  const int bn = blockIdx.y * BN;
  const int wr = (BN == 128) ? (w >> 1) : w;
  const int wc = (BN == 128) ? (w & 1) : 0;

  f32x4 acc[FI][4];
#pragma unroll
  for (int i = 0; i < FI; ++i)
#pragma unroll
    for (int j = 0; j < 4; ++j) acc[i][j] = (f32x4)0.f;

  for (int k0 = 0; k0 < K; k0 += 32) {
#pragma unroll
    for (int s = 0; s < 2; ++s) {
      const int inst = w * 2 + s;
      const int row = inst * 16 + (lane >> 2);
      int rg = bm + row;
      if (rg > M - 1) rg = M - 1;
      const int c = (lane & 3) ^ ((row >> 1) & 3);
      gload_lds16(A + (size_t)rg * K + k0 + c * 8, &As[inst * 512]);
    }
    if (BN == 128) {
#pragma unroll
      for (int s = 0; s < 2; ++s) {
        const int inst = w * 2 + s;
        const int row = inst * 16 + (lane >> 2);
        const int c = (lane & 3) ^ ((row >> 1) & 3);
        gload_lds16(Bt + (size_t)(bn + row) * K + k0 + c * 8,
                    &Bs[inst * 512]);
      }
    } else {
      const int inst = w;
      const int row = inst * 16 + (lane >> 2);
      const int c = (lane & 3) ^ ((row >> 1) & 3);
      gload_lds16(Bt + (size_t)(bn + row) * K + k0 + c * 8, &Bs[inst * 512]);
    }
    __syncthreads();

    const int kc = lane >> 4;
    short8 af[FI], bfr[4];
#pragma unroll
    for (int i = 0; i < FI; ++i) {
      const int row = wr * WROWS + i * 16 + (lane & 15);
      const int ch = kc ^ ((row >> 1) & 3);
      af[i] = *reinterpret_cast<const short8*>(&As[row * 32 + ch * 8]);
    }
#pragma unroll
    for (int j = 0; j < 4; ++j) {
      const int row = wc * 64 + j * 16 + (lane & 15);
      const int ch = kc ^ ((row >> 1) & 3);
      bfr[j] = *reinterpret_cast<const short8*>(&Bs[row * 32 + ch * 8]);
    }
#pragma unroll
    for (int i = 0; i < FI; ++i)
#pragma unroll
      for (int j = 0; j < 4; ++j)
        acc[i][j] = __builtin_amdgcn_mfma_f32_16x16x32_bf16(af[i], bfr[j],
                                                            acc[i][j], 0, 0, 0);
    __syncthreads();
  }

#pragma unroll
  for (int i = 0; i < FI; ++i) {
#pragma unroll
    for (int j = 0; j < 4; ++j) {
      const int col = bn + wc * 64 + j * 16 + (lane & 15);
      const float bv = bias[col];
#pragma unroll
      for (int r = 0; r < 4; ++r) {
        const int row = bm + wr * WROWS + i * 16 + (lane >> 4) * 4 + r;
        if (row < M) {
          float o = acc[i][j][r] + bv;
          if (RELU_OUT) o = fmaxf(o, 0.f);
          C[(size_t)row * N + col] = f2bf(o);
        }
      }
    }
  }
}

// ---------------------------------------------------------------------------
// conversions
// ---------------------------------------------------------------------------
__global__ __launch_bounds__(256) void cvt_bf16(const float4* __restrict__ in,
                                                ushort4* __restrict__ out,
                                                int n4) {
  const int i = blockIdx.x * 256 + threadIdx.x;
  if (i >= n4) return;
  const float4 v = in[i];
  ushort4 o;
  o.x = f2bf(v.x); o.y = f2bf(v.y); o.z = f2bf(v.z); o.w = f2bf(v.w);
  out[i] = o;
}

__global__ __launch_bounds__(256) void wt_transpose(const float* __restrict__ W,
                                                    u16* __restrict__ Wt,
                                                    int K, int N) {
  const int i = blockIdx.x * 256 + threadIdx.x;
  if (i >= N * K) return;
  const int n = i / K;
  const int k = i - n * K;
  Wt[i] = f2bf(W[(size_t)k * N + n]);
}

// ---------------------------------------------------------------------------
// Bucket radix partition (deterministic, no global atomics) + per-bucket
// counting sort -> fully row-sorted CSR (edges2, rptr).
// ---------------------------------------------------------------------------
__global__ __launch_bounds__(256) void p1_hist(const int* __restrict__ rows,
                                               int* __restrict__ cnt) {
  __shared__ int h[NBUCK];
  const int tid = threadIdx.x;
  for (int i = tid; i < NBUCK; i += 256) h[i] = 0;
  __syncthreads();
  const int s = blockIdx.x * CHUNK;
  const int e = s + CHUNK;
  for (int i = s + tid; i < e && i < NE; i += 256)
    atomicAdd(&h[rows[i] >> 6], 1);
  __syncthreads();
  for (int i = tid; i < NBUCK; i += 256) cnt[i * PBLK + blockIdx.x] = h[i];
}

__global__ __launch_bounds__(256) void s1_scan_blocks(int* __restrict__ cnt,
                                                      int* __restrict__ btot) {
  __shared__ int lds[256];
  const int bu = blockIdx.x;
  const int t = threadIdx.x;
  const int v = cnt[bu * PBLK + t];
  lds[t] = v;
  __syncthreads();
#pragma unroll
  for (int off = 1; off < 256; off <<= 1) {
    const int x = (t >= off) ? lds[t - off] : 0;
    __syncthreads();
    lds[t] += x;
    __syncthreads();
  }
  cnt[bu * PBLK + t] = lds[t] - v;
  if (t == 255) btot[bu] = lds[255];
}

__global__ __launch_bounds__(1024) void s2_scan_buckets(
    const int* __restrict__ btot, int* __restrict__ bstart) {
  __shared__ int lds[1024];
  __shared__ int carry;
  const int t = threadIdx.x;
  if (t == 0) carry = 0;
  __syncthreads();
  for (int base = 0; base < NBUCK; base += 1024) {
    const int i = base + t;
    const int v = (i < NBUCK) ? btot[i] : 0;
    lds[t] = v;
    __syncthreads();
#pragma unroll
    for (int off = 1; off < 1024; off <<= 1) {
      const int x = (t >= off) ? lds[t - off] : 0;
      __syncthreads();
      lds[t] += x;
      __syncthreads();
    }
    const int excl = lds[t] - v;
    const int c = carry;
    if (i < NBUCK) bstart[i] = c + excl;
    __syncthreads();
    if (t == 0) carry = c + lds[1023];
    __syncthreads();
  }
  if (t == 0) bstart[NBUCK] = NE;
}

__global__ __launch_bounds__(256) void p3_scatter(
    const int* __restrict__ rows, const int* __restrict__ cols,
    const float* __restrict__ vals, const int* __restrict__ cnt,
    const int* __restrict__ bstart, int2* __restrict__ edges) {
  __shared__ int lcur[NBUCK];
  const int tid = threadIdx.x;
  const int blk = blockIdx.x;
  for (int bu = tid; bu < NBUCK; bu += 256)
    lcur[bu] = bstart[bu] + cnt[bu * PBLK + blk];
  __syncthreads();
  const int s = blk * CHUNK;
  const int e = s + CHUNK;
  for (int i = s + tid; i < e && i < NE; i += 256) {
    const int r = rows[i];
    const int bu = r >> 6;
    const int lr = r & 63;
    const int pos = atomicAdd(&lcur[bu], 1);
    edges[pos] = make_int2(cols[i] | (lr << 17), __float_as_int(vals[i]));
  }
}

// Per-bucket counting sort -> row-sorted edges2 + rptr. One block per bucket.
// Bucket region (~16KB) is L2-resident for the second pass.
__global__ __launch_bounds__(256) void sort_bucket(
    const int* __restrict__ bstart, const int2* __restrict__ edges,
    int2* __restrict__ edges2, int* __restrict__ rptr) {
  __shared__ int hist[RPB];
  __shared__ int sc[RPB];
  __shared__ int cur[RPB];
  const int bu = blockIdx.x;
  const int t = threadIdx.x;
  const int s = bstart[bu], e = bstart[bu + 1];
  if (t < RPB) hist[t] = 0;
  __syncthreads();
  for (int i = s + t; i < e; i += 256)
    atomicAdd(&hist[(edges[i].x >> 17) & 63], 1);
  __syncthreads();
  const int hv = (t < RPB) ? hist[t] : 0;
  if (t < RPB) sc[t] = hv;
  __syncthreads();
#pragma unroll
  for (int off = 1; off < RPB; off <<= 1) {
    const int x = (t >= off && t < RPB) ? sc[t - off] : 0;
    __syncthreads();
    if (t < RPB) sc[t] += x;
    __syncthreads();
  }
  if (t < RPB) {
    const int base = s + sc[t] - hv;  // exclusive
    cur[t] = base;
    const int grow = bu * RPB + t;
    if (grow < NN) rptr[grow] = base;
  }
  if (bu == 0 && t == 0) rptr[NN] = NE;
  __syncthreads();
  for (int i = s + t; i < e; i += 256) {
    const int2 ed = edges[i];
    const int lr = (ed.x >> 17) & 63;
    const int pos = atomicAdd(&cur[lr], 1);
    edges2[pos] = make_int2(ed.x & 0x1FFFF, ed.y);
  }
}

// ---------------------------------------------------------------------------
// CSR SpMM width 256 (bf16 in, relu+bf16 out). One wave/row, lane = 4 cols.
// unroll 8 for deep MLP.
// ---------------------------------------------------------------------------
__global__ __launch_bounds__(256) void spmm256_csr(
    const int* __restrict__ ptr, const int2* __restrict__ edges,
    const u16* __restrict__ Zb, u16* __restrict__ Yb) {
  const int wid = (int)((blockIdx.x * (size_t)256 + threadIdx.x) >> 6);
  const int lane = threadIdx.x & 63;
  if (wid >= NN) return;
  const int s = ptr[wid], e = ptr[wid + 1];
  float a0 = 0.f, a1 = 0.f, a2 = 0.f, a3 = 0.f;
  int j = s;
  for (; j + 7 < e; j += 8) {
    int2 ed[8];
#pragma unroll
    for (int q = 0; q < 8; ++q) ed[q] = edges[j + q];
    ushort4 u[8];
#pragma unroll
    for (int q = 0; q < 8; ++q)
      u[q] = reinterpret_cast<const ushort4*>(Zb + (size_t)ed[q].x * 256)[lane];
#pragma unroll
    for (int q = 0; q < 8; ++q) {
      const float v = __int_as_float(ed[q].y);
      a0 += v * bf2f(u[q].x);
      a1 += v * bf2f(u[q].y);
      a2 += v * bf2f(u[q].z);
      a3 += v * bf2f(u[q].w);
    }
  }
  for (; j < e; ++j) {
    const int2 e0 = edges[j];
    const ushort4 u0 =
        reinterpret_cast<const ushort4*>(Zb + (size_t)e0.x * 256)[lane];
    const float v0 = __int_as_float(e0.y);
    a0 += v0 * bf2f(u0.x);
    a1 += v0 * bf2f(u0.y);
    a2 += v0 * bf2f(u0.z);
    a3 += v0 * bf2f(u0.w);
  }
  ushort4 o;  // fused relu + bf16
  o.x = f2bf(fmaxf(a0, 0.f));
  o.y = f2bf(fmaxf(a1, 0.f));
  o.z = f2bf(fmaxf(a2, 0.f));
  o.w = f2bf(fmaxf(a3, 0.f));
  reinterpret_cast<ushort4*>(Yb + (size_t)wid * 256)[lane] = o;
}

// ---------------------------------------------------------------------------
// CSR SpMM width 64 (bf16 in, fp32 out). One wave/row, lane = 1 col. unroll 8.
// ---------------------------------------------------------------------------
__global__ __launch_bounds__(256) void spmm64_csr(
    const int* __restrict__ ptr, const int2* __restrict__ edges,
    const u16* __restrict__ Zb, float* __restrict__ Y) {
  const int wid = (int)((blockIdx.x * (size_t)256 + threadIdx.x) >> 6);
  const int lane = threadIdx.x & 63;
  if (wid >= NN) return;
  const int s = ptr[wid], e = ptr[wid + 1];
  float acc = 0.f;
  int j = s;
  for (; j + 7 < e; j += 8) {
    int2 ed[8];
#pragma unroll
    for (int q = 0; q < 8; ++q) ed[q] = edges[j + q];
    u16 u[8];
#pragma unroll
    for (int q = 0; q < 8; ++q) u[q] = Zb[(size_t)ed[q].x * 64 + lane];
#pragma unroll
    for (int q = 0; q < 8; ++q)
      acc += __int_as_float(ed[q].y) * bf2f(u[q]);
  }
  for (; j < e; ++j)
    acc += __int_as_float(edges[j].y) * bf2f(Zb[(size_t)edges[j].x * 64 + lane]);
  Y[(size_t)wid * 64 + lane] = acc;
}

extern "C" void kernel_launch(void* const* d_in, const int* in_sizes, int n_in,
                              void* d_out, int out_size, void* d_ws,
                              size_t ws_size, hipStream_t stream) {
  const float* x_a  = (const float*)d_in[0];
  const float* x_b  = (const float*)d_in[1];
  const int*   rows = (const int*)d_in[2];
  const int*   cols = (const int*)d_in[3];
  const float* vals = (const float*)d_in[4];
  const float* W1a  = (const float*)d_in[5];
  const float* b1a  = (const float*)d_in[6];
  const float* W1b  = (const float*)d_in[7];
  const float* b1b  = (const float*)d_in[8];
  const float* Wf   = (const float*)d_in[9];
  const float* bf   = (const float*)d_in[10];
  const float* W2   = (const float*)d_in[11];
  const float* b2   = (const float*)d_in[12];
  float* out = (float*)d_out;

  // workspace (~185 MB); edges2 aliases xab/xbb (dead after gemm1/2)
  char* p = (char*)d_ws;
  u16* h    = (u16*)p;  p += (size_t)NN * NHID * 2;   // h, later s1b
  u16* zb   = (u16*)p;  p += (size_t)NN * NHID * 2;
  u16* z2b  = (u16*)p;  p += (size_t)NN * NOUT * 2;
  u16* xab  = (u16*)p;  p += (size_t)NA * 256 * 2;    // \ edges2 aliases
  u16* xbb  = (u16*)p;  p += (size_t)NB * 128 * 2;    // /  (40.9MB >= 25.6MB)
  u16* W1at = (u16*)p;  p += 256 * 256 * 2;
  u16* W1bt = (u16*)p;  p += 256 * 128 * 2;
  u16* Wft  = (u16*)p;  p += 256 * 256 * 2;
  u16* W2t  = (u16*)p;  p += 64 * 256 * 2;
  int2* edges = (int2*)p; p += (size_t)NE * 8;
  int* cnt    = (int*)p;  p += (size_t)NBUCK * PBLK * 4;  // 1.6MB
  int* btot   = (int*)p;  p += (size_t)((NBUCK + 3) & ~3) * 4;
  int* bstart = (int*)p;  p += (size_t)((NBUCK + 4) & ~3) * 4;
  int* rptr   = (int*)p;  p += (size_t)(NN + 4) * 4;
  u16* s1b = h;
  int2* edges2 = (int2*)xab;

  // --- conversions + dense pipeline through gemm3 (xab/xbb live here) ---
  cvt_bf16<<<(NA * 256 / 4 + 255) / 256, 256, 0, stream>>>(
      (const float4*)x_a, (ushort4*)xab, NA * 256 / 4);
  cvt_bf16<<<(NB * 128 / 4 + 255) / 256, 256, 0, stream>>>(
      (const float4*)x_b, (ushort4*)xbb, NB * 128 / 4);
  wt_transpose<<<(256 * 256 + 255) / 256, 256, 0, stream>>>(W1a, W1at, 256, 256);
  wt_transpose<<<(256 * 128 + 255) / 256, 256, 0, stream>>>(W1b, W1bt, 128, 256);
  wt_transpose<<<(256 * 256 + 255) / 256, 256, 0, stream>>>(Wf, Wft, 256, 256);
  wt_transpose<<<(64 * 256 + 255) / 256, 256, 0, stream>>>(W2, W2t, 256, 64);

  gemm_mfma<128, 1><<<dim3((NA + 127) / 128, 2), 256, 0, stream>>>(
      xab, W1at, b1a, h, NA, NHID, 256);
  gemm_mfma<128, 1><<<dim3((NB + 127) / 128, 2), 256, 0, stream>>>(
      xbb, W1bt, b1b, h + (size_t)NA * NHID, NB, NHID, 128);
  gemm_mfma<128, 0><<<dim3((NN + 127) / 128, 2), 256, 0, stream>>>(
      h, Wft, bf, zb, NN, NHID, 256);

  // --- CSR build (xab/xbb now dead; edges2 reuses their space) ---
  p1_hist<<<PBLK, 256, 0, stream>>>(rows, cnt);
  s1_scan_blocks<<<NBUCK, 256, 0, stream>>>(cnt, btot);
  s2_scan_buckets<<<1, 1024, 0, stream>>>(btot, bstart);
  p3_scatter<<<PBLK, 256, 0, stream>>>(rows, cols, vals, cnt, bstart, edges);
  sort_bucket<<<NBUCK, 256, 0, stream>>>(bstart, edges, edges2, rptr);

  // --- sparse + tail ---
  // s1b = bf16(relu(spmm(zb)))
  spmm256_csr<<<(NN * 64 + 255) / 256, 256, 0, stream>>>(rptr, edges2, zb, s1b);
  gemm_mfma<64, 0><<<dim3((NN + 127) / 128, 1), 256, 0, stream>>>(
      s1b, W2t, b2, z2b, NN, NOUT, 256);
  // out = spmm(z2b)
  spmm64_csr<<<(NN * 64 + 255) / 256, 256, 0, stream>>>(rptr, edges2, z2b, out);
}

// Round 6
// 585.463 us; speedup vs baseline: 10.3567x; 1.0062x over previous
//
#include <hip/hip_runtime.h>

#define NN 100000
#define NE 3200000
#define NA 60000
#define NB 40000
#define NHID 256
#define NOUT 64

#define RPB 64                    // rows per bucket
#define NBUCK 1563                // ceil(NN/64)
#define PBLK 256                  // partition blocks
#define CHUNK 12500               // NE / PBLK (exact)

typedef unsigned short u16;
typedef unsigned int u32;
typedef __attribute__((ext_vector_type(8))) short short8;
typedef __attribute__((ext_vector_type(4))) float f32x4;

__device__ __forceinline__ float bf2f(u16 u) {
  return __uint_as_float(((u32)u) << 16);
}
__device__ __forceinline__ u16 f2bf(float f) {
  u32 u = __float_as_uint(f);
  u32 r = (u + 0x7fffu + ((u >> 16) & 1u)) >> 16;  // RNE
  return (u16)r;
}

__device__ __forceinline__ void gload_lds16(const void* gsrc, void* ldst) {
  __builtin_amdgcn_global_load_lds(
      (const __attribute__((address_space(1))) void*)gsrc,
      (__attribute__((address_space(3))) void*)ldst, 16, 0, 0);
}

// ---------------------------------------------------------------------------
// bf16 MFMA GEMM (round-3 proven): C = A @ Bt^T + bias, opt relu.
// ---------------------------------------------------------------------------
template <int BN, int RELU_OUT>
__global__ __launch_bounds__(256) void gemm_mfma(
    const u16* __restrict__ A, const u16* __restrict__ Bt,
    const float* __restrict__ bias, u16* __restrict__ C,
    int M, int N, int K) {
  constexpr int BM = 128;
  constexpr int FI = (BN == 128) ? 4 : 2;
  constexpr int WROWS = FI * 16;
  __shared__ __align__(16) u16 As[BM * 32];
  __shared__ __align__(16) u16 Bs[BN * 32];

  const int tid = threadIdx.x;
  const int w = tid >> 6;
  const int lane = tid & 63;
  const int bm = blockIdx.x * BM;
  const int bn = blockIdx.y * BN;
  const int wr = (BN == 128) ? (w >> 1) : w;
  const int wc = (BN == 128) ? (w & 1) : 0;

  f32x4 acc[FI][4];
#pragma unroll
  for (int i = 0; i < FI; ++i)
#pragma unroll
    for (int j = 0; j < 4; ++j) acc[i][j] = (f32x4)0.f;

  for (int k0 = 0; k0 < K; k0 += 32) {
#pragma unroll
    for (int s = 0; s < 2; ++s) {
      const int inst = w * 2 + s;
      const int row = inst * 16 + (lane >> 2);
      int rg = bm + row;
      if (rg > M - 1) rg = M - 1;
      const int c = (lane & 3) ^ ((row >> 1) & 3);
      gload_lds16(A + (size_t)rg * K + k0 + c * 8, &As[inst * 512]);
    }
    if (BN == 128) {
#pragma unroll
      for (int s = 0; s < 2; ++s) {
        const int inst = w * 2 + s;
        const int row = inst * 16 + (lane >> 2);
        const int c = (lane & 3) ^ ((row >> 1) & 3);
        gload_lds16(Bt + (size_t)(bn + row) * K + k0 + c * 8,
                    &Bs[inst * 512]);
      }
    } else {
      const int inst = w;
      const int row = inst * 16 + (lane >> 2);
      const int c = (lane & 3) ^ ((row >> 1) & 3);
      gload_lds16(Bt + (size_t)(bn + row) * K + k0 + c * 8, &Bs[inst * 512]);
    }
    __syncthreads();

    const int kc = lane >> 4;
    short8 af[FI], bfr[4];
#pragma unroll
    for (int i = 0; i < FI; ++i) {
      const int row = wr * WROWS + i * 16 + (lane & 15);
      const int ch = kc ^ ((row >> 1) & 3);
      af[i] = *reinterpret_cast<const short8*>(&As[row * 32 + ch * 8]);
    }
#pragma unroll
    for (int j = 0; j < 4; ++j) {
      const int row = wc * 64 + j * 16 + (lane & 15);
      const int ch = kc ^ ((row >> 1) & 3);
      bfr[j] = *reinterpret_cast<const short8*>(&Bs[row * 32 + ch * 8]);
    }
#pragma unroll
    for (int i = 0; i < FI; ++i)
#pragma unroll
      for (int j = 0; j < 4; ++j)
        acc[i][j] = __builtin_amdgcn_mfma_f32_16x16x32_bf16(af[i], bfr[j],
                                                            acc[i][j], 0, 0, 0);
    __syncthreads();
  }

#pragma unroll
  for (int i = 0; i < FI; ++i) {
#pragma unroll
    for (int j = 0; j < 4; ++j) {
      const int col = bn + wc * 64 + j * 16 + (lane & 15);
      const float bv = bias[col];
#pragma unroll
      for (int r = 0; r < 4; ++r) {
        const int row = bm + wr * WROWS + i * 16 + (lane >> 4) * 4 + r;
        if (row < M) {
          float o = acc[i][j][r] + bv;
          if (RELU_OUT) o = fmaxf(o, 0.f);
          C[(size_t)row * N + col] = f2bf(o);
        }
      }
    }
  }
}

// ---------------------------------------------------------------------------
// conversions
// ---------------------------------------------------------------------------
__global__ __launch_bounds__(256) void cvt_bf16(const float4* __restrict__ in,
                                                ushort4* __restrict__ out,
                                                int n4) {
  const int i = blockIdx.x * 256 + threadIdx.x;
  if (i >= n4) return;
  const float4 v = in[i];
  ushort4 o;
  o.x = f2bf(v.x); o.y = f2bf(v.y); o.z = f2bf(v.z); o.w = f2bf(v.w);
  out[i] = o;
}

__global__ __launch_bounds__(256) void wt_transpose(const float* __restrict__ W,
                                                    u16* __restrict__ Wt,
                                                    int K, int N) {
  const int i = blockIdx.x * 256 + threadIdx.x;
  if (i >= N * K) return;
  const int n = i / K;
  const int k = i - n * K;
  Wt[i] = f2bf(W[(size_t)k * N + n]);
}

// ---------------------------------------------------------------------------
// Bucket radix partition (deterministic, no global atomics) + per-bucket
// counting sort -> fully row-sorted CSR (edges2, rptr).
// ---------------------------------------------------------------------------
__global__ __launch_bounds__(256) void p1_hist(const int* __restrict__ rows,
                                               int* __restrict__ cnt) {
  __shared__ int h[NBUCK];
  const int tid = threadIdx.x;
  for (int i = tid; i < NBUCK; i += 256) h[i] = 0;
  __syncthreads();
  const int s = blockIdx.x * CHUNK;
  const int e = s + CHUNK;
  for (int i = s + tid; i < e && i < NE; i += 256)
    atomicAdd(&h[rows[i] >> 6], 1);
  __syncthreads();
  for (int i = tid; i < NBUCK; i += 256) cnt[i * PBLK + blockIdx.x] = h[i];
}

__global__ __launch_bounds__(256) void s1_scan_blocks(int* __restrict__ cnt,
                                                      int* __restrict__ btot) {
  __shared__ int lds[256];
  const int bu = blockIdx.x;
  const int t = threadIdx.x;
  const int v = cnt[bu * PBLK + t];
  lds[t] = v;
  __syncthreads();
#pragma unroll
  for (int off = 1; off < 256; off <<= 1) {
    const int x = (t >= off) ? lds[t - off] : 0;
    __syncthreads();
    lds[t] += x;
    __syncthreads();
  }
  cnt[bu * PBLK + t] = lds[t] - v;
  if (t == 255) btot[bu] = lds[255];
}

__global__ __launch_bounds__(1024) void s2_scan_buckets(
    const int* __restrict__ btot, int* __restrict__ bstart) {
  __shared__ int lds[1024];
  __shared__ int carry;
  const int t = threadIdx.x;
  if (t == 0) carry = 0;
  __syncthreads();
  for (int base = 0; base < NBUCK; base += 1024) {
    const int i = base + t;
    const int v = (i < NBUCK) ? btot[i] : 0;
    lds[t] = v;
    __syncthreads();
#pragma unroll
    for (int off = 1; off < 1024; off <<= 1) {
      const int x = (t >= off) ? lds[t - off] : 0;
      __syncthreads();
      lds[t] += x;
      __syncthreads();
    }
    const int excl = lds[t] - v;
    const int c = carry;
    if (i < NBUCK) bstart[i] = c + excl;
    __syncthreads();
    if (t == 0) carry = c + lds[1023];
    __syncthreads();
  }
  if (t == 0) bstart[NBUCK] = NE;
}

__global__ __launch_bounds__(256) void p3_scatter(
    const int* __restrict__ rows, const int* __restrict__ cols,
    const float* __restrict__ vals, const int* __restrict__ cnt,
    const int* __restrict__ bstart, int2* __restrict__ edges) {
  __shared__ int lcur[NBUCK];
  const int tid = threadIdx.x;
  const int blk = blockIdx.x;
  for (int bu = tid; bu < NBUCK; bu += 256)
    lcur[bu] = bstart[bu] + cnt[bu * PBLK + blk];
  __syncthreads();
  const int s = blk * CHUNK;
  const int e = s + CHUNK;
  for (int i = s + tid; i < e && i < NE; i += 256) {
    const int r = rows[i];
    const int bu = r >> 6;
    const int lr = r & 63;
    const int pos = atomicAdd(&lcur[bu], 1);
    edges[pos] = make_int2(cols[i] | (lr << 17), __float_as_int(vals[i]));
  }
}

// Per-bucket counting sort -> row-sorted edges2 + rptr. One block per bucket.
__global__ __launch_bounds__(256) void sort_bucket(
    const int* __restrict__ bstart, const int2* __restrict__ edges,
    int2* __restrict__ edges2, int* __restrict__ rptr) {
  __shared__ int hist[RPB];
  __shared__ int sc[RPB];
  __shared__ int cur[RPB];
  const int bu = blockIdx.x;
  const int t = threadIdx.x;
  const int s = bstart[bu], e = bstart[bu + 1];
  if (t < RPB) hist[t] = 0;
  __syncthreads();
  for (int i = s + t; i < e; i += 256)
    atomicAdd(&hist[(edges[i].x >> 17) & 63], 1);
  __syncthreads();
  const int hv = (t < RPB) ? hist[t] : 0;
  if (t < RPB) sc[t] = hv;
  __syncthreads();
#pragma unroll
  for (int off = 1; off < RPB; off <<= 1) {
    const int x = (t >= off && t < RPB) ? sc[t - off] : 0;
    __syncthreads();
    if (t < RPB) sc[t] += x;
    __syncthreads();
  }
  if (t < RPB) {
    const int base = s + sc[t] - hv;  // exclusive
    cur[t] = base;
    const int grow = bu * RPB + t;
    if (grow < NN) rptr[grow] = base;
  }
  if (bu == 0 && t == 0) rptr[NN] = NE;
  __syncthreads();
  for (int i = s + t; i < e; i += 256) {
    const int2 ed = edges[i];
    const int lr = (ed.x >> 17) & 63;
    const int pos = atomicAdd(&cur[lr], 1);
    edges2[pos] = make_int2(ed.x & 0x1FFFF, ed.y);
  }
}

// ---------------------------------------------------------------------------
// CSR SpMM width 256 (bf16 in, relu+bf16 out). One wave/row, lane = 4 cols.
// unroll 16 for deep MLP (latency-bound gather).
// ---------------------------------------------------------------------------
__global__ __launch_bounds__(256) void spmm256_csr(
    const int* __restrict__ ptr, const int2* __restrict__ edges,
    const u16* __restrict__ Zb, u16* __restrict__ Yb) {
  const int wid = (int)((blockIdx.x * (size_t)256 + threadIdx.x) >> 6);
  const int lane = threadIdx.x & 63;
  if (wid >= NN) return;
  const int s = ptr[wid], e = ptr[wid + 1];
  float a0 = 0.f, a1 = 0.f, a2 = 0.f, a3 = 0.f;
  int j = s;
  for (; j + 15 < e; j += 16) {
    int2 ed[16];
#pragma unroll
    for (int q = 0; q < 16; ++q) ed[q] = edges[j + q];
    ushort4 u[16];
#pragma unroll
    for (int q = 0; q < 16; ++q)
      u[q] = reinterpret_cast<const ushort4*>(Zb + (size_t)ed[q].x * 256)[lane];
#pragma unroll
    for (int q = 0; q < 16; ++q) {
      const float v = __int_as_float(ed[q].y);
      a0 += v * bf2f(u[q].x);
      a1 += v * bf2f(u[q].y);
      a2 += v * bf2f(u[q].z);
      a3 += v * bf2f(u[q].w);
    }
  }
  if (j + 7 < e) {
    int2 ed[8];
#pragma unroll
    for (int q = 0; q < 8; ++q) ed[q] = edges[j + q];
    ushort4 u[8];
#pragma unroll
    for (int q = 0; q < 8; ++q)
      u[q] = reinterpret_cast<const ushort4*>(Zb + (size_t)ed[q].x * 256)[lane];
#pragma unroll
    for (int q = 0; q < 8; ++q) {
      const float v = __int_as_float(ed[q].y);
      a0 += v * bf2f(u[q].x);
      a1 += v * bf2f(u[q].y);
      a2 += v * bf2f(u[q].z);
      a3 += v * bf2f(u[q].w);
    }
    j += 8;
  }
  for (; j < e; ++j) {
    const int2 e0 = edges[j];
    const ushort4 u0 =
        reinterpret_cast<const ushort4*>(Zb + (size_t)e0.x * 256)[lane];
    const float v0 = __int_as_float(e0.y);
    a0 += v0 * bf2f(u0.x);
    a1 += v0 * bf2f(u0.y);
    a2 += v0 * bf2f(u0.z);
    a3 += v0 * bf2f(u0.w);
  }
  ushort4 o;  // fused relu + bf16
  o.x = f2bf(fmaxf(a0, 0.f));
  o.y = f2bf(fmaxf(a1, 0.f));
  o.z = f2bf(fmaxf(a2, 0.f));
  o.w = f2bf(fmaxf(a3, 0.f));
  reinterpret_cast<ushort4*>(Yb + (size_t)wid * 256)[lane] = o;
}

// ---------------------------------------------------------------------------
// CSR SpMM width 64 (bf16 in, fp32 out). One wave/row, lane = 1 col. unroll 16.
// ---------------------------------------------------------------------------
__global__ __launch_bounds__(256) void spmm64_csr(
    const int* __restrict__ ptr, const int2* __restrict__ edges,
    const u16* __restrict__ Zb, float* __restrict__ Y) {
  const int wid = (int)((blockIdx.x * (size_t)256 + threadIdx.x) >> 6);
  const int lane = threadIdx.x & 63;
  if (wid >= NN) return;
  const int s = ptr[wid], e = ptr[wid + 1];
  float acc = 0.f;
  int j = s;
  for (; j + 15 < e; j += 16) {
    int2 ed[16];
#pragma unroll
    for (int q = 0; q < 16; ++q) ed[q] = edges[j + q];
    u16 u[16];
#pragma unroll
    for (int q = 0; q < 16; ++q) u[q] = Zb[(size_t)ed[q].x * 64 + lane];
#pragma unroll
    for (int q = 0; q < 16; ++q)
      acc += __int_as_float(ed[q].y) * bf2f(u[q]);
  }
  if (j + 7 < e) {
    int2 ed[8];
#pragma unroll
    for (int q = 0; q < 8; ++q) ed[q] = edges[j + q];
    u16 u[8];
#pragma unroll
    for (int q = 0; q < 8; ++q) u[q] = Zb[(size_t)ed[q].x * 64 + lane];
#pragma unroll
    for (int q = 0; q < 8; ++q)
      acc += __int_as_float(ed[q].y) * bf2f(u[q]);
    j += 8;
  }
  for (; j < e; ++j)
    acc += __int_as_float(edges[j].y) * bf2f(Zb[(size_t)edges[j].x * 64 + lane]);
  Y[(size_t)wid * 64 + lane] = acc;
}

extern "C" void kernel_launch(void* const* d_in, const int* in_sizes, int n_in,
                              void* d_out, int out_size, void* d_ws,
                              size_t ws_size, hipStream_t stream) {
  const float* x_a  = (const float*)d_in[0];
  const float* x_b  = (const float*)d_in[1];
  const int*   rows = (const int*)d_in[2];
  const int*   cols = (const int*)d_in[3];
  const float* vals = (const float*)d_in[4];
  const float* W1a  = (const float*)d_in[5];
  const float* b1a  = (const float*)d_in[6];
  const float* W1b  = (const float*)d_in[7];
  const float* b1b  = (const float*)d_in[8];
  const float* Wf   = (const float*)d_in[9];
  const float* bf   = (const float*)d_in[10];
  const float* W2   = (const float*)d_in[11];
  const float* b2   = (const float*)d_in[12];
  float* out = (float*)d_out;

  // workspace (~185 MB); edges2 aliases xab/xbb (dead after gemm1/2)
  char* p = (char*)d_ws;
  u16* h    = (u16*)p;  p += (size_t)NN * NHID * 2;   // h, later s1b
  u16* zb   = (u16*)p;  p += (size_t)NN * NHID * 2;
  u16* z2b  = (u16*)p;  p += (size_t)NN * NOUT * 2;
  u16* xab  = (u16*)p;  p += (size_t)NA * 256 * 2;    // \ edges2 aliases
  u16* xbb  = (u16*)p;  p += (size_t)NB * 128 * 2;    // /  (40.9MB >= 25.6MB)
  u16* W1at = (u16*)p;  p += 256 * 256 * 2;
  u16* W1bt = (u16*)p;  p += 256 * 128 * 2;
  u16* Wft  = (u16*)p;  p += 256 * 256 * 2;
  u16* W2t  = (u16*)p;  p += 64 * 256 * 2;
  int2* edges = (int2*)p; p += (size_t)NE * 8;
  int* cnt    = (int*)p;  p += (size_t)NBUCK * PBLK * 4;  // 1.6MB
  int* btot   = (int*)p;  p += (size_t)((NBUCK + 3) & ~3) * 4;
  int* bstart = (int*)p;  p += (size_t)((NBUCK + 4) & ~3) * 4;
  int* rptr   = (int*)p;  p += (size_t)(NN + 4) * 4;
  u16* s1b = h;
  int2* edges2 = (int2*)xab;

  // --- conversions + dense pipeline through gemm3 (xab/xbb live here) ---
  cvt_bf16<<<(NA * 256 / 4 + 255) / 256, 256, 0, stream>>>(
      (const float4*)x_a, (ushort4*)xab, NA * 256 / 4);
  cvt_bf16<<<(NB * 128 / 4 + 255) / 256, 256, 0, stream>>>(
      (const float4*)x_b, (ushort4*)xbb, NB * 128 / 4);
  wt_transpose<<<(256 * 256 + 255) / 256, 256, 0, stream>>>(W1a, W1at, 256, 256);
  wt_transpose<<<(256 * 128 + 255) / 256, 256, 0, stream>>>(W1b, W1bt, 128, 256);
  wt_transpose<<<(256 * 256 + 255) / 256, 256, 0, stream>>>(Wf, Wft, 256, 256);
  wt_transpose<<<(64 * 256 + 255) / 256, 256, 0, stream>>>(W2, W2t, 256, 64);

  gemm_mfma<128, 1><<<dim3((NA + 127) / 128, 2), 256, 0, stream>>>(
      xab, W1at, b1a, h, NA, NHID, 256);
  gemm_mfma<128, 1><<<dim3((NB + 127) / 128, 2), 256, 0, stream>>>(
      xbb, W1bt, b1b, h + (size_t)NA * NHID, NB, NHID, 128);
  gemm_mfma<128, 0><<<dim3((NN + 127) / 128, 2), 256, 0, stream>>>(
      h, Wft, bf, zb, NN, NHID, 256);

  // --- CSR build (xab/xbb now dead; edges2 reuses their space) ---
  p1_hist<<<PBLK, 256, 0, stream>>>(rows, cnt);
  s1_scan_blocks<<<NBUCK, 256, 0, stream>>>(cnt, btot);
  s2_scan_buckets<<<1, 1024, 0, stream>>>(btot, bstart);
  p3_scatter<<<PBLK, 256, 0, stream>>>(rows, cols, vals, cnt, bstart, edges);
  sort_bucket<<<NBUCK, 256, 0, stream>>>(bstart, edges, edges2, rptr);

  // --- sparse + tail ---
  // s1b = bf16(relu(spmm(zb)))
  spmm256_csr<<<(NN * 64 + 255) / 256, 256, 0, stream>>>(rptr, edges2, zb, s1b);
  gemm_mfma<64, 0><<<dim3((NN + 127) / 128, 1), 256, 0, stream>>>(
      s1b, W2t, b2, z2b, NN, NOUT, 256);
  // out = spmm(z2b)
  spmm64_csr<<<(NN * 64 + 255) / 256, 256, 0, stream>>>(rptr, edges2, z2b, out);
}

// Round 7
// 501.740 us; speedup vs baseline: 12.0849x; 1.1669x over previous
//
#include <hip/hip_runtime.h>

#define NN 100000
#define NE 3200000
#define NA 60000
#define NB 40000
#define NHID 256
#define NOUT 64

#define RPB 64                    // rows per bucket
#define NBUCK 1563                // ceil(NN/64)
#define PBLK 256                  // partition blocks
#define CHUNK 12500               // NE / PBLK (exact)

typedef unsigned short u16;
typedef unsigned int u32;
typedef __attribute__((ext_vector_type(8))) short short8;
typedef __attribute__((ext_vector_type(4))) float f32x4;

__device__ __forceinline__ float bf2f(u16 u) {
  return __uint_as_float(((u32)u) << 16);
}
__device__ __forceinline__ u16 f2bf(float f) {
  u32 u = __float_as_uint(f);
  u32 r = (u + 0x7fffu + ((u >> 16) & 1u)) >> 16;  // RNE
  return (u16)r;
}
// sign-extend byte b of dw to float
__device__ __forceinline__ float i8f(u32 dw, int b) {
  return (float)((int)(dw << (24 - 8 * b)) >> 24);
}

__device__ __forceinline__ void gload_lds16(const void* gsrc, void* ldst) {
  __builtin_amdgcn_global_load_lds(
      (const __attribute__((address_space(1))) void*)gsrc,
      (__attribute__((address_space(3))) void*)ldst, 16, 0, 0);
}

// ---------------------------------------------------------------------------
// bf16 MFMA GEMM: C = A @ Bt^T + bias.
// QUANT=0: bf16 out (opt relu). QUANT=1 (BN=128 only): int8 out with
// per-row-per-64col scale; bytes packed lane-major (feature f=64g+16j+m
// stored at byte pos p=64g+4m+j) -- consumer-side compensated via W2t perm.
// ---------------------------------------------------------------------------
template <int BN, int RELU_OUT, int QUANT>
__global__ __launch_bounds__(256) void gemm_mfma(
    const u16* __restrict__ A, const u16* __restrict__ Bt,
    const float* __restrict__ bias, void* __restrict__ Cout,
    float* __restrict__ scales, int M, int N, int K) {
  constexpr int BM = 128;
  constexpr int FI = (BN == 128) ? 4 : 2;
  constexpr int WROWS = FI * 16;
  __shared__ __align__(16) u16 As[BM * 32];
  __shared__ __align__(16) u16 Bs[BN * 32];

  const int tid = threadIdx.x;
  const int w = tid >> 6;
  const int lane = tid & 63;
  const int bm = blockIdx.x * BM;
  const int bn = blockIdx.y * BN;
  const int wr = (BN == 128) ? (w >> 1) : w;
  const int wc = (BN == 128) ? (w & 1) : 0;

  f32x4 acc[FI][4];
#pragma unroll
  for (int i = 0; i < FI; ++i)
#pragma unroll
    for (int j = 0; j < 4; ++j) acc[i][j] = (f32x4)0.f;

  for (int k0 = 0; k0 < K; k0 += 32) {
#pragma unroll
    for (int s = 0; s < 2; ++s) {
      const int inst = w * 2 + s;
      const int row = inst * 16 + (lane >> 2);
      int rg = bm + row;
      if (rg > M - 1) rg = M - 1;
      const int c = (lane & 3) ^ ((row >> 1) & 3);
      gload_lds16(A + (size_t)rg * K + k0 + c * 8, &As[inst * 512]);
    }
    if (BN == 128) {
#pragma unroll
      for (int s = 0; s < 2; ++s) {
        const int inst = w * 2 + s;
        const int row = inst * 16 + (lane >> 2);
        const int c = (lane & 3) ^ ((row >> 1) & 3);
        gload_lds16(Bt + (size_t)(bn + row) * K + k0 + c * 8,
                    &Bs[inst * 512]);
      }
    } else {
      const int inst = w;
      const int row = inst * 16 + (lane >> 2);
      const int c = (lane & 3) ^ ((row >> 1) & 3);
      gload_lds16(Bt + (size_t)(bn + row) * K + k0 + c * 8, &Bs[inst * 512]);
    }
    __syncthreads();

    const int kc = lane >> 4;
    short8 af[FI], bfr[4];
#pragma unroll
    for (int i = 0; i < FI; ++i) {
      const int row = wr * WROWS + i * 16 + (lane & 15);
      const int ch = kc ^ ((row >> 1) & 3);
      af[i] = *reinterpret_cast<const short8*>(&As[row * 32 + ch * 8]);
    }
#pragma unroll
    for (int j = 0; j < 4; ++j) {
      const int row = wc * 64 + j * 16 + (lane & 15);
      const int ch = kc ^ ((row >> 1) & 3);
      bfr[j] = *reinterpret_cast<const short8*>(&Bs[row * 32 + ch * 8]);
    }
#pragma unroll
    for (int i = 0; i < FI; ++i)
#pragma unroll
      for (int j = 0; j < 4; ++j)
        acc[i][j] = __builtin_amdgcn_mfma_f32_16x16x32_bf16(af[i], bfr[j],
                                                            acc[i][j], 0, 0, 0);
    __syncthreads();
  }

  if constexpr (QUANT) {
    // int8 quant epilogue (BN=128, N=256)
    float bv[4];
#pragma unroll
    for (int j = 0; j < 4; ++j)
      bv[j] = bias[bn + wc * 64 + j * 16 + (lane & 15)];
    const int g = (bn >> 6) + wc;  // 64-col block index 0..3
    u32* zq = (u32*)Cout;
#pragma unroll
    for (int i = 0; i < FI; ++i) {
#pragma unroll
      for (int r = 0; r < 4; ++r) {
        float o[4];
#pragma unroll
        for (int j = 0; j < 4; ++j) o[j] = acc[i][j][r] + bv[j];
        float am = fmaxf(fmaxf(fabsf(o[0]), fabsf(o[1])),
                         fmaxf(fabsf(o[2]), fabsf(o[3])));
#pragma unroll
        for (int mk = 1; mk < 16; mk <<= 1) am = fmaxf(am, __shfl_xor(am, mk));
        const float sinv = am > 0.f ? 127.f / am : 0.f;
        const float sc = am > 0.f ? am / 127.f : 0.f;
        const int q0 = __float2int_rn(o[0] * sinv);
        const int q1 = __float2int_rn(o[1] * sinv);
        const int q2 = __float2int_rn(o[2] * sinv);
        const int q3 = __float2int_rn(o[3] * sinv);
        const u32 dw = (q0 & 0xff) | ((q1 & 0xff) << 8) | ((q2 & 0xff) << 16) |
                       ((q3 & 0xff) << 24);
        const int row = bm + wr * WROWS + i * 16 + (lane >> 4) * 4 + r;
        if (row < M) {
          zq[(size_t)row * 64 + g * 16 + (lane & 15)] = dw;
          if ((lane & 15) == 0) scales[(size_t)row * 4 + g] = sc;
        }
      }
    }
  } else {
    u16* C = (u16*)Cout;
#pragma unroll
    for (int i = 0; i < FI; ++i) {
#pragma unroll
      for (int j = 0; j < 4; ++j) {
        const int col = bn + wc * 64 + j * 16 + (lane & 15);
        const float bv = bias[col];
#pragma unroll
        for (int r = 0; r < 4; ++r) {
          const int row = bm + wr * WROWS + i * 16 + (lane >> 4) * 4 + r;
          if (row < M) {
            float o = acc[i][j][r] + bv;
            if (RELU_OUT) o = fmaxf(o, 0.f);
            C[(size_t)row * N + col] = f2bf(o);
          }
        }
      }
    }
  }
}

// ---------------------------------------------------------------------------
// conversions
// ---------------------------------------------------------------------------
__global__ __launch_bounds__(256) void cvt_bf16(const float4* __restrict__ in,
                                                ushort4* __restrict__ out,
                                                int n4) {
  const int i = blockIdx.x * 256 + threadIdx.x;
  if (i >= n4) return;
  const float4 v = in[i];
  ushort4 o;
  o.x = f2bf(v.x); o.y = f2bf(v.y); o.z = f2bf(v.z); o.w = f2bf(v.w);
  out[i] = o;
}

// All 4 weight transposes in one launch. W2t additionally applies the
// int8 storage permutation: W2t[n*256+p] = W2[f(p)*64+n],
// f(p) = 64*(p>>6) + 16*(p&3) + ((p>>2)&15).
__global__ __launch_bounds__(256) void wt_all(
    const float* __restrict__ W1a, const float* __restrict__ W1b,
    const float* __restrict__ Wf, const float* __restrict__ W2,
    u16* __restrict__ W1at, u16* __restrict__ W1bt, u16* __restrict__ Wft,
    u16* __restrict__ W2t) {
  const int i = blockIdx.x * 256 + threadIdx.x;
  if (i < 65536) {                       // W1a [256,256] -> [256,256]
    const int n = i >> 8, k = i & 255;
    W1at[i] = f2bf(W1a[k * 256 + n]);
  } else if (i < 98304) {                // W1b [128,256] -> [256,128]
    const int t = i - 65536;
    const int n = t >> 7, k = t & 127;
    W1bt[t] = f2bf(W1b[k * 256 + n]);
  } else if (i < 163840) {               // Wf [256,256] -> [256,256]
    const int t = i - 98304;
    const int n = t >> 8, k = t & 255;
    Wft[t] = f2bf(Wf[k * 256 + n]);
  } else if (i < 180224) {               // W2 [256,64] -> [64,256] permuted
    const int t = i - 163840;
    const int n = t >> 8, p = t & 255;
    const int f = ((p >> 6) << 6) + ((p & 3) << 4) + ((p >> 2) & 15);
    W2t[t] = f2bf(W2[f * 64 + n]);
  }
}

// ---------------------------------------------------------------------------
// Bucket radix partition + per-bucket counting sort -> row-sorted CSR.
// ---------------------------------------------------------------------------
__global__ __launch_bounds__(256) void p1_hist(const int* __restrict__ rows,
                                               int* __restrict__ cnt) {
  __shared__ int h[NBUCK];
  const int tid = threadIdx.x;
  for (int i = tid; i < NBUCK; i += 256) h[i] = 0;
  __syncthreads();
  const int s = blockIdx.x * CHUNK;
  const int e = s + CHUNK;
  for (int i = s + tid; i < e; i += 256) atomicAdd(&h[rows[i] >> 6], 1);
  __syncthreads();
  for (int i = tid; i < NBUCK; i += 256) cnt[i * PBLK + blockIdx.x] = h[i];
}

__global__ __launch_bounds__(256) void s1_scan_blocks(int* __restrict__ cnt,
                                                      int* __restrict__ btot) {
  __shared__ int lds[256];
  const int bu = blockIdx.x;
  const int t = threadIdx.x;
  const int v = cnt[bu * PBLK + t];
  lds[t] = v;
  __syncthreads();
#pragma unroll
  for (int off = 1; off < 256; off <<= 1) {
    const int x = (t >= off) ? lds[t - off] : 0;
    __syncthreads();
    lds[t] += x;
    __syncthreads();
  }
  cnt[bu * PBLK + t] = lds[t] - v;
  if (t == 255) btot[bu] = lds[255];
}

__global__ __launch_bounds__(1024) void s2_scan_buckets(
    const int* __restrict__ btot, int* __restrict__ bstart) {
  __shared__ int lds[1024];
  __shared__ int carry;
  const int t = threadIdx.x;
  if (t == 0) carry = 0;
  __syncthreads();
  for (int base = 0; base < NBUCK; base += 1024) {
    const int i = base + t;
    const int v = (i < NBUCK) ? btot[i] : 0;
    lds[t] = v;
    __syncthreads();
#pragma unroll
    for (int off = 1; off < 1024; off <<= 1) {
      const int x = (t >= off) ? lds[t - off] : 0;
      __syncthreads();
      lds[t] += x;
      __syncthreads();
    }
    const int excl = lds[t] - v;
    const int c = carry;
    if (i < NBUCK) bstart[i] = c + excl;
    __syncthreads();
    if (t == 0) carry = c + lds[1023];
    __syncthreads();
  }
  if (t == 0) bstart[NBUCK] = NE;
}

__global__ __launch_bounds__(256) void p3_scatter(
    const int* __restrict__ rows, const int* __restrict__ cols,
    const float* __restrict__ vals, const int* __restrict__ cnt,
    const int* __restrict__ bstart, int2* __restrict__ edges) {
  __shared__ int lcur[NBUCK];
  const int tid = threadIdx.x;
  const int blk = blockIdx.x;
  for (int bu = tid; bu < NBUCK; bu += 256)
    lcur[bu] = bstart[bu] + cnt[bu * PBLK + blk];
  __syncthreads();
  const int s = blk * CHUNK;
  const int e = s + CHUNK;
  for (int i = s + tid; i < e; i += 256) {
    const int r = rows[i];
    const int bu = r >> 6;
    const int lr = r & 63;
    const int pos = atomicAdd(&lcur[bu], 1);
    edges[pos] = make_int2(cols[i] | (lr << 17), __float_as_int(vals[i]));
  }
}

__global__ __launch_bounds__(256) void sort_bucket(
    const int* __restrict__ bstart, const int2* __restrict__ edges,
    int2* __restrict__ edges2, int* __restrict__ rptr) {
  __shared__ int hist[RPB];
  __shared__ int sc[RPB];
  __shared__ int cur[RPB];
  const int bu = blockIdx.x;
  const int t = threadIdx.x;
  const int s = bstart[bu], e = bstart[bu + 1];
  if (t < RPB) hist[t] = 0;
  __syncthreads();
  for (int i = s + t; i < e; i += 256)
    atomicAdd(&hist[(edges[i].x >> 17) & 63], 1);
  __syncthreads();
  const int hv = (t < RPB) ? hist[t] : 0;
  if (t < RPB) sc[t] = hv;
  __syncthreads();
#pragma unroll
  for (int off = 1; off < RPB; off <<= 1) {
    const int x = (t >= off && t < RPB) ? sc[t - off] : 0;
    __syncthreads();
    if (t < RPB) sc[t] += x;
    __syncthreads();
  }
  if (t < RPB) {
    const int base = s + sc[t] - hv;
    cur[t] = base;
    const int grow = bu * RPB + t;
    if (grow < NN) rptr[grow] = base;
  }
  if (bu == 0 && t == 0) rptr[NN] = NE;
  __syncthreads();
  for (int i = s + t; i < e; i += 256) {
    const int2 ed = edges[i];
    const int lr = (ed.x >> 17) & 63;
    const int pos = atomicAdd(&cur[lr], 1);
    edges2[pos] = make_int2(ed.x & 0x1FFFF, ed.y);
  }
}

// ---------------------------------------------------------------------------
// CSR SpMM width 256, int8-quantized input (per-row-per-64col scale),
// relu+bf16 out. One wave/row, lane = 1 dword (4 features). unroll 8.
// ---------------------------------------------------------------------------
__global__ __launch_bounds__(256) void spmm256_q8(
    const int* __restrict__ ptr, const int2* __restrict__ edges,
    const u32* __restrict__ Zq, const float* __restrict__ scales,
    u16* __restrict__ Yb) {
  const int wid = (int)((blockIdx.x * (size_t)256 + threadIdx.x) >> 6);
  const int lane = threadIdx.x & 63;
  if (wid >= NN) return;
  const int s = ptr[wid], e = ptr[wid + 1];
  const int gsel = lane >> 4;
  float a0 = 0.f, a1 = 0.f, a2 = 0.f, a3 = 0.f;
  int j = s;
  for (; j + 7 < e; j += 8) {
    int2 ed[8];
#pragma unroll
    for (int q = 0; q < 8; ++q) ed[q] = edges[j + q];
    u32 dw[8];
    float sc[8];
#pragma unroll
    for (int q = 0; q < 8; ++q) {
      dw[q] = Zq[(size_t)ed[q].x * 64 + lane];
      sc[q] = scales[(size_t)ed[q].x * 4 + gsel];
    }
#pragma unroll
    for (int q = 0; q < 8; ++q) {
      const float vs = __int_as_float(ed[q].y) * sc[q];
      a0 += vs * i8f(dw[q], 0);
      a1 += vs * i8f(dw[q], 1);
      a2 += vs * i8f(dw[q], 2);
      a3 += vs * i8f(dw[q], 3);
    }
  }
  for (; j < e; ++j) {
    const int2 e0 = edges[j];
    const u32 dw = Zq[(size_t)e0.x * 64 + lane];
    const float vs =
        __int_as_float(e0.y) * scales[(size_t)e0.x * 4 + gsel];
    a0 += vs * i8f(dw, 0);
    a1 += vs * i8f(dw, 1);
    a2 += vs * i8f(dw, 2);
    a3 += vs * i8f(dw, 3);
  }
  ushort4 o;  // relu + bf16 (output stays in permuted feature order)
  o.x = f2bf(fmaxf(a0, 0.f));
  o.y = f2bf(fmaxf(a1, 0.f));
  o.z = f2bf(fmaxf(a2, 0.f));
  o.w = f2bf(fmaxf(a3, 0.f));
  reinterpret_cast<ushort4*>(Yb + (size_t)wid * 256)[lane] = o;
}

// ---------------------------------------------------------------------------
// CSR SpMM width 64 (bf16 in, fp32 out). One wave/row, lane = 1 col. unroll 8.
// ---------------------------------------------------------------------------
__global__ __launch_bounds__(256) void spmm64_csr(
    const int* __restrict__ ptr, const int2* __restrict__ edges,
    const u16* __restrict__ Zb, float* __restrict__ Y) {
  const int wid = (int)((blockIdx.x * (size_t)256 + threadIdx.x) >> 6);
  const int lane = threadIdx.x & 63;
  if (wid >= NN) return;
  const int s = ptr[wid], e = ptr[wid + 1];
  float acc = 0.f;
  int j = s;
  for (; j + 7 < e; j += 8) {
    int2 ed[8];
#pragma unroll
    for (int q = 0; q < 8; ++q) ed[q] = edges[j + q];
    u16 u[8];
#pragma unroll
    for (int q = 0; q < 8; ++q) u[q] = Zb[(size_t)ed[q].x * 64 + lane];
#pragma unroll
    for (int q = 0; q < 8; ++q)
      acc += __int_as_float(ed[q].y) * bf2f(u[q]);
  }
  for (; j < e; ++j)
    acc += __int_as_float(edges[j].y) * bf2f(Zb[(size_t)edges[j].x * 64 + lane]);
  Y[(size_t)wid * 64 + lane] = acc;
}

extern "C" void kernel_launch(void* const* d_in, const int* in_sizes, int n_in,
                              void* d_out, int out_size, void* d_ws,
                              size_t ws_size, hipStream_t stream) {
  const float* x_a  = (const float*)d_in[0];
  const float* x_b  = (const float*)d_in[1];
  const int*   rows = (const int*)d_in[2];
  const int*   cols = (const int*)d_in[3];
  const float* vals = (const float*)d_in[4];
  const float* W1a  = (const float*)d_in[5];
  const float* b1a  = (const float*)d_in[6];
  const float* W1b  = (const float*)d_in[7];
  const float* b1b  = (const float*)d_in[8];
  const float* Wf   = (const float*)d_in[9];
  const float* bf   = (const float*)d_in[10];
  const float* W2   = (const float*)d_in[11];
  const float* b2   = (const float*)d_in[12];
  float* out = (float*)d_out;

  // workspace (~163 MB); edges2 aliases xab/xbb (dead after gemm1/2)
  char* p = (char*)d_ws;
  u16* h    = (u16*)p;  p += (size_t)NN * NHID * 2;   // h, later s1b
  u32* zq   = (u32*)p;  p += (size_t)NN * 64 * 4;     // 25.6MB int8 z
  float* zscale = (float*)p; p += (size_t)NN * 4 * 4; // 1.6MB
  u16* z2b  = (u16*)p;  p += (size_t)NN * NOUT * 2;
  u16* xab  = (u16*)p;  p += (size_t)NA * 256 * 2;    // \ edges2 aliases
  u16* xbb  = (u16*)p;  p += (size_t)NB * 128 * 2;    // /  (40.9MB >= 25.6MB)
  u16* W1at = (u16*)p;  p += 256 * 256 * 2;
  u16* W1bt = (u16*)p;  p += 256 * 128 * 2;
  u16* Wft  = (u16*)p;  p += 256 * 256 * 2;
  u16* W2t  = (u16*)p;  p += 64 * 256 * 2;
  int2* edges = (int2*)p; p += (size_t)NE * 8;
  int* cnt    = (int*)p;  p += (size_t)NBUCK * PBLK * 4;
  int* btot   = (int*)p;  p += (size_t)((NBUCK + 3) & ~3) * 4;
  int* bstart = (int*)p;  p += (size_t)((NBUCK + 4) & ~3) * 4;
  int* rptr   = (int*)p;  p += (size_t)(NN + 4) * 4;
  u16* s1b = h;
  int2* edges2 = (int2*)xab;

  // --- conversions ---
  cvt_bf16<<<(NA * 256 / 4 + 255) / 256, 256, 0, stream>>>(
      (const float4*)x_a, (ushort4*)xab, NA * 256 / 4);
  cvt_bf16<<<(NB * 128 / 4 + 255) / 256, 256, 0, stream>>>(
      (const float4*)x_b, (ushort4*)xbb, NB * 128 / 4);
  wt_all<<<704, 256, 0, stream>>>(W1a, W1b, Wf, W2, W1at, W1bt, Wft, W2t);

  // --- dense pipeline through gemm3 (xab/xbb live here) ---
  gemm_mfma<128, 1, 0><<<dim3((NA + 127) / 128, 2), 256, 0, stream>>>(
      xab, W1at, b1a, h, nullptr, NA, NHID, 256);
  gemm_mfma<128, 1, 0><<<dim3((NB + 127) / 128, 2), 256, 0, stream>>>(
      xbb, W1bt, b1b, h + (size_t)NA * NHID, nullptr, NB, NHID, 128);
  // zq = int8(h @ Wf + bf), per-64col scales
  gemm_mfma<128, 0, 1><<<dim3((NN + 127) / 128, 2), 256, 0, stream>>>(
      h, Wft, bf, zq, zscale, NN, NHID, 256);

  // --- CSR build (xab/xbb now dead; edges2 reuses their space) ---
  p1_hist<<<PBLK, 256, 0, stream>>>(rows, cnt);
  s1_scan_blocks<<<NBUCK, 256, 0, stream>>>(cnt, btot);
  s2_scan_buckets<<<1, 1024, 0, stream>>>(btot, bstart);
  p3_scatter<<<PBLK, 256, 0, stream>>>(rows, cols, vals, cnt, bstart, edges);
  sort_bucket<<<NBUCK, 256, 0, stream>>>(bstart, edges, edges2, rptr);

  // --- sparse + tail ---
  // s1b = bf16(relu(spmm(zq)))   (permuted feature order; W2t compensates)
  spmm256_q8<<<(NN * 64 + 255) / 256, 256, 0, stream>>>(rptr, edges2, zq,
                                                        zscale, s1b);
  gemm_mfma<64, 0, 0><<<dim3((NN + 127) / 128, 1), 256, 0, stream>>>(
      s1b, W2t, b2, z2b, nullptr, NN, NOUT, 256);
  // out = spmm(z2b)
  spmm64_csr<<<(NN * 64 + 255) / 256, 256, 0, stream>>>(rptr, edges2, z2b, out);
}